// Round 10
// baseline (344.350 us; speedup 1.0000x reference)
//
#include <hip/hip_runtime.h>
#include <math.h>

// GRUDetector: B=1024, T=512, F=64, H=128, gates (r,z,n), + MLP head (H->32->1).
// R10: R7/R9 step (1622 cyc) = [DS 576 || MFMA 700] -> [gates ~550 EXPOSED]
// (lockstep waves: MFMA pipe idle during trans/VALU gates phase). Fix =
// cx-chaining: U's x-region holds x(t+1); at step t, after the h-update,
// 6 x-side MFMAs compute NEXT step's x-contribution cx = bias + W_ih x(t+1)
// during the gates phase; step t+1's post-barrier path is 12 h-MFMAs chained
// on ready cx C-operands. h-frags ds_read first; cnx snapshotted so x-MFMAs
// hoist freely. NB=16, 64 blocks (B/16 tiles is the natural width; R9 showed
// NB=8 wastes cols: per-SIMD work invariant). AGPR pins in-loop (R9-proven).

#define Bsz  1024
#define Tlen 512
#define Fdim 64
#define Hdim 128
#define Gdim 384
#define NB   16
#define NTHR 512
#define NBLK (Bsz / NB)   // 64

typedef __attribute__((ext_vector_type(8))) _Float16 f16x8;
typedef __attribute__((ext_vector_type(4))) _Float16 f16x4;
typedef __attribute__((ext_vector_type(2))) _Float16 f16x2;
typedef __attribute__((ext_vector_type(4))) float    f32x4;

__device__ __forceinline__ float fast_sigmoid(float v) {
    return __builtin_amdgcn_rcpf(1.f + __expf(-v));
}
__device__ __forceinline__ float fast_tanh(float v) {
    return 1.f - 2.f * __builtin_amdgcn_rcpf(__expf(2.f * v) + 1.f);
}

__global__ void
__attribute__((amdgpu_flat_work_group_size(NTHR, NTHR), amdgpu_waves_per_eu(2, 2)))
gru_mfma(const float* __restrict__ x,
         const float* __restrict__ W_ih, const float* __restrict__ W_hh,
         const float* __restrict__ b_ih, const float* __restrict__ b_hh,
         const float* __restrict__ W1, const float* __restrict__ b1,
         const float* __restrict__ W2, const float* __restrict__ b2,
         float* __restrict__ out)
{
    __shared__ __align__(16) _Float16 WH[24 * 4 * 4 * 128];  // 98,304 B
    __shared__ __align__(16) _Float16 WI[24 * 2 * 4 * 128];  // 49,152 B
    __shared__ __align__(16) _Float16 U0[6 * 4 * 16 * 8];    //  6,144 B
    __shared__ __align__(16) _Float16 U1[6 * 4 * 16 * 8];    //  6,144 B  (156 KB)

    const int tid  = threadIdx.x;
    const int w    = tid >> 6;        // wave 0..7: gate rows 16w..16w+15
    const int l    = tid & 63;
    const int q    = l >> 4;
    const int bcol = l & 15;
    const int b0   = blockIdx.x * NB;

    // ---- stage W_hh, W_ih into LDS in A-fragment layout (one-time)
    for (int i = tid; i < Gdim * Hdim; i += NTHR) {
        int gr = i >> 7, k = i & 127;
        int idx = (((gr >> 4) * 4 + (k >> 5)) * 4 + ((k & 31) >> 3)) * 128
                + (gr & 15) * 8 + (k & 7);
        WH[idx] = (_Float16)W_hh[i];
    }
    for (int i = tid; i < Gdim * Fdim; i += NTHR) {
        int gr = i >> 6, k = i & 63;
        int idx = (((gr >> 4) * 2 + (k >> 5)) * 4 + ((k & 31) >> 3)) * 128
                + (gr & 15) * 8 + (k & 7);
        WI[idx] = (_Float16)W_ih[i];
    }
    for (int i = tid; i < 2048; i += NTHR) U0[i] = (_Float16)0.f;  // h(0) = 0
    {   // stage x(0) into U0.x
        int e = tid * 2, bx_ = e >> 6, j = e & 63;
        float2 xv = *reinterpret_cast<const float2*>(
            &x[((size_t)(b0 + bx_) * Tlen + 0) * Fdim + j]);
        int kk = 128 + j;
        int idx = (((kk >> 5) * 4 + ((kk & 31) >> 3)) * 16 + bx_) * 8 + (kk & 7);
        U0[idx]     = (_Float16)xv.x;
        U0[idx + 1] = (_Float16)xv.y;
    }

    // ---- per-lane biases (gate rows 16w + q*4 + j)
    float br[4], bz[4], bnh[4], bnx[4];
    #pragma unroll
    for (int j = 0; j < 4; ++j) {
        int gr = 16 * w + q * 4 + j;
        br[j]  = b_ih[gr] + b_hh[gr];
        bz[j]  = b_ih[Hdim + gr] + b_hh[Hdim + gr];
        bnh[j] = b_hh[2 * Hdim + gr];
        bnx[j] = b_ih[2 * Hdim + gr];
    }

    float hp0 = 0.f, hp1 = 0.f, hp2 = 0.f, hp3 = 0.f;

    const int kb    = 16 * w + 4 * q;
    const int hbase = (((kb >> 5) * 4 + ((kb & 31) >> 3)) * 16 + bcol) * 8 + (kb & 7);

    const int e_x = tid * 2, bx = e_x >> 6, jx = e_x & 63;
    const int kx  = 128 + jx;
    const int xidx = (((kx >> 5) * 4 + ((kx & 31) >> 3)) * 16 + bx) * 8 + (kx & 7);
    const float* xsrc = &x[(size_t)(b0 + bx) * Tlen * Fdim + jx];

    __syncthreads();

#define WHF(gt, kt) (*reinterpret_cast<const f16x8*>(&WH[((((gt)*4+(kt))*4+q)*128) + (l&15)*8]))
#define WIF(gt, kt) (*reinterpret_cast<const f16x8*>(&WI[((((gt)*2+(kt))*4+q)*128) + (l&15)*8]))
#define MFMA(a, b, c) __builtin_amdgcn_mfma_f32_16x16x32_f16((a), (b), (c), 0, 0, 0)

    // ---- load 18 weight fragments once (AGPR-pinned in-loop)
    f16x8 whr0 = WHF(w, 0),      whr1 = WHF(w, 1),      whr2 = WHF(w, 2),      whr3 = WHF(w, 3);
    f16x8 whz0 = WHF(8 + w, 0),  whz1 = WHF(8 + w, 1),  whz2 = WHF(8 + w, 2),  whz3 = WHF(8 + w, 3);
    f16x8 whn0 = WHF(16 + w, 0), whn1 = WHF(16 + w, 1), whn2 = WHF(16 + w, 2), whn3 = WHF(16 + w, 3);
    f16x8 wir0 = WIF(w, 0),      wir1 = WIF(w, 1);
    f16x8 wiz0 = WIF(8 + w, 0),  wiz1 = WIF(8 + w, 1);
    f16x8 win0 = WIF(16 + w, 0), win1 = WIF(16 + w, 1);

    // ---- pre-loop: x-contribution accumulators for t=0 from x(0)
    f32x4 cxr, cxz, cxn;
    {
        f16x8 ub4 = *reinterpret_cast<const f16x8*>(&U0[((4*4+q)*16 + bcol)*8]);
        f16x8 ub5 = *reinterpret_cast<const f16x8*>(&U0[((5*4+q)*16 + bcol)*8]);
        cxr = f32x4{br[0], br[1], br[2], br[3]};
        cxz = f32x4{bz[0], bz[1], bz[2], bz[3]};
        cxn = f32x4{bnx[0], bnx[1], bnx[2], bnx[3]};
        cxr = MFMA(wir0, ub4, cxr); cxr = MFMA(wir1, ub5, cxr);
        cxz = MFMA(wiz0, ub4, cxz); cxz = MFMA(wiz1, ub5, cxz);
        cxn = MFMA(win0, ub4, cxn); cxn = MFMA(win1, ub5, cxn);
    }
    __syncthreads();               // x(0) frag reads done before overwrite

    {   // restage U0.x with x(1)
        float2 x1 = *reinterpret_cast<const float2*>(xsrc + (size_t)1 * Fdim);
        f16x2 xq = {(_Float16)x1.x, (_Float16)x1.y};
        *reinterpret_cast<f16x2*>(&U0[xidx]) = xq;
    }
    // xp holds x(t+2) entering step t
    float2 xp = *reinterpret_cast<const float2*>(xsrc + (size_t)2 * Fdim);
    __syncthreads();

    auto step = [&](const _Float16* __restrict__ Ur, _Float16* __restrict__ Uw, int t) {
        // in-loop AGPR pins: loop-carried opaque values -> no remat, no copies
        asm volatile("" : "+a"(whr0), "+a"(whr1), "+a"(whr2), "+a"(whr3),
                          "+a"(whz0), "+a"(whz1));
        asm volatile("" : "+a"(whz2), "+a"(whz3), "+a"(whn0), "+a"(whn1),
                          "+a"(whn2), "+a"(whn3));
        asm volatile("" : "+a"(wir0), "+a"(wir1), "+a"(wiz0), "+a"(wiz1),
                          "+a"(win0), "+a"(win1));

        // h fragments first (critical path), then x(t+1) fragments
        f16x8 ub0 = *reinterpret_cast<const f16x8*>(&Ur[((0*4+q)*16 + bcol)*8]);
        f16x8 ub1 = *reinterpret_cast<const f16x8*>(&Ur[((1*4+q)*16 + bcol)*8]);
        f16x8 ub2 = *reinterpret_cast<const f16x8*>(&Ur[((2*4+q)*16 + bcol)*8]);
        f16x8 ub3 = *reinterpret_cast<const f16x8*>(&Ur[((3*4+q)*16 + bcol)*8]);
        f16x8 ub4 = *reinterpret_cast<const f16x8*>(&Ur[((4*4+q)*16 + bcol)*8]);
        f16x8 ub5 = *reinterpret_cast<const f16x8*>(&Ur[((5*4+q)*16 + bcol)*8]);

        float2 xw = xp;                                   // x(t+2)
        if (t + 3 < Tlen)
            xp = *reinterpret_cast<const float2*>(xsrc + (size_t)(t + 3) * Fdim);

        // 12 h-MFMAs chained on ready cx C-operands
        f32x4 cr  = cxr;
        f32x4 cz  = cxz;
        f32x4 cnh = {bnh[0], bnh[1], bnh[2], bnh[3]};
        f32x4 cnxu = cxn;              // snapshot: frees cxn for next-step accum

        cr  = MFMA(whr0, ub0, cr);
        cz  = MFMA(whz0, ub0, cz);
        cnh = MFMA(whn0, ub0, cnh);
        cr  = MFMA(whr1, ub1, cr);
        cz  = MFMA(whz1, ub1, cz);
        cnh = MFMA(whn1, ub1, cnh);
        cr  = MFMA(whr2, ub2, cr);
        cz  = MFMA(whz2, ub2, cz);
        cnh = MFMA(whn2, ub2, cnh);
        cr  = MFMA(whr3, ub3, cr);
        cz  = MFMA(whz3, ub3, cz);
        cnh = MFMA(whn3, ub3, cnh);

        // next-step x contributions (fill MFMA pipe during gates phase)
        cxr = f32x4{br[0], br[1], br[2], br[3]};
        cxz = f32x4{bz[0], bz[1], bz[2], bz[3]};
        cxn = f32x4{bnx[0], bnx[1], bnx[2], bnx[3]};
        cxr = MFMA(wir0, ub4, cxr); cxr = MFMA(wir1, ub5, cxr);
        cxz = MFMA(wiz0, ub4, cxz); cxz = MFMA(wiz1, ub5, cxz);
        cxn = MFMA(win0, ub4, cxn); cxn = MFMA(win1, ub5, cxn);

        // gates
        float r0 = fast_sigmoid(cr[0]), z0 = fast_sigmoid(cz[0]);
        float r1 = fast_sigmoid(cr[1]), z1 = fast_sigmoid(cz[1]);
        float r2 = fast_sigmoid(cr[2]), z2 = fast_sigmoid(cz[2]);
        float r3 = fast_sigmoid(cr[3]), z3 = fast_sigmoid(cz[3]);
        float n0 = fast_tanh(cnxu[0] + r0 * cnh[0]);
        float n1 = fast_tanh(cnxu[1] + r1 * cnh[1]);
        float n2 = fast_tanh(cnxu[2] + r2 * cnh[2]);
        float n3 = fast_tanh(cnxu[3] + r3 * cnh[3]);
        hp0 = n0 + z0 * (hp0 - n0);
        hp1 = n1 + z1 * (hp1 - n1);
        hp2 = n2 + z2 * (hp2 - n2);
        hp3 = n3 + z3 * (hp3 - n3);

        f16x4 hq = {(_Float16)hp0, (_Float16)hp1, (_Float16)hp2, (_Float16)hp3};
        *reinterpret_cast<f16x4*>(&Uw[hbase]) = hq;

        if (t + 2 < Tlen) {                               // stage x(t+2)
            f16x2 xq = {(_Float16)xw.x, (_Float16)xw.y};
            *reinterpret_cast<f16x2*>(&Uw[xidx]) = xq;
        }
        __syncthreads();   // single barrier: Uw complete, Ur reads done
    };

    #pragma unroll 1
    for (int t = 0; t < Tlen; t += 2) {
        step(U0, U1, t);
        step(U1, U0, t + 1);
    }
    // final h(T) in U0

    // ---- epilogue MLP: hidden = relu(hT @ W1.T + b1); out = hidden @ W2.T + b2
    {
        int m = tid & 31, b = tid >> 5;
        float acc = b1[m];
        #pragma unroll 8
        for (int k = 0; k < Hdim; ++k) {
            int ui = (((k >> 5) * 4 + ((k & 31) >> 3)) * 16 + b) * 8 + (k & 7);
            acc += W1[m * Hdim + k] * (float)U0[ui];
        }
        float v = W2[m] * fmaxf(acc, 0.f);
        v += __shfl_xor(v, 1,  32);
        v += __shfl_xor(v, 2,  32);
        v += __shfl_xor(v, 4,  32);
        v += __shfl_xor(v, 8,  32);
        v += __shfl_xor(v, 16, 32);
        if (m == 0) out[b0 + b] = v + b2[0];
    }
}

extern "C" void kernel_launch(void* const* d_in, const int* in_sizes, int n_in,
                              void* d_out, int out_size, void* d_ws, size_t ws_size,
                              hipStream_t stream)
{
    const float* x    = (const float*)d_in[0];
    const float* W_ih = (const float*)d_in[1];
    const float* W_hh = (const float*)d_in[2];
    const float* b_ih = (const float*)d_in[3];
    const float* b_hh = (const float*)d_in[4];
    const float* W1   = (const float*)d_in[5];
    const float* b1   = (const float*)d_in[6];
    const float* W2   = (const float*)d_in[7];
    const float* b2   = (const float*)d_in[8];
    float* out = (float*)d_out;

    dim3 grid(NBLK), block(NTHR);
    hipLaunchKernelGGL(gru_mfma, grid, block, 0, stream,
                       x, W_ih, W_hh, b_ih, b_hh, W1, b1, W2, b2, out);
}